// Round 1
// baseline (254.381 us; speedup 1.0000x reference)
//
#include <hip/hip_runtime.h>

#define B 4
#define TQ 256
#define TK 1024
#define QS 512
#define NN 128

// exp(2y) = exp2(y * 2*log2(e)); we pre-scale the projections by this in K1.
#define TANH_SCALE 2.8853900817779268f
#define LOG2E 1.4426950408889634f

__device__ __forceinline__ float fast_exp2(float x) {
#if __has_builtin(__builtin_amdgcn_exp2f)
    return __builtin_amdgcn_exp2f(x);
#else
    return exp2f(x);
#endif
}
__device__ __forceinline__ float fast_rcp(float x) {
#if __has_builtin(__builtin_amdgcn_rcpf)
    return __builtin_amdgcn_rcpf(x);
#else
    return 1.0f / x;
#endif
}

// ---------------------------------------------------------------------------
// K1: fused projections. Row space = [1024 query rows ; 4096 keys rows].
// Each block: 32 rows x 128 cols, BK=32, 256 threads, 4x4 microtile.
// Epilogue multiplies by TANH_SCALE (2*log2 e) so K2 can use exp2 directly.
// ---------------------------------------------------------------------------
__global__ __launch_bounds__(256) void proj_kernel(
    const float* __restrict__ query, const float* __restrict__ keys,
    const float* __restrict__ Wq, const float* __restrict__ Wk,
    float* attq, float* attk)
{
    __shared__ float As[32][36];   // [kk][row], transposed; pad keeps 16B align
    __shared__ float Bs[32][128];  // [kk][n]

    const int tid = threadIdx.x;
    const int rb = blockIdx.x * 32;          // first row of this block
    const bool isq = (rb < B * TQ);
    const float* A = isq ? (query + (size_t)rb * QS)
                         : (keys + (size_t)(rb - B * TQ) * QS);
    const float* W = isq ? Wq : Wk;
    float* out = isq ? (attq + (size_t)rb * NN)
                     : (attk + (size_t)(rb - B * TQ) * NN);

    const int n0 = (tid & 31) * 4;   // 32 col-groups cover 128 cols
    const int q0 = (tid >> 5) * 4;   // 8 row-groups cover 32 rows
    float acc[4][4] = {};

    for (int k0 = 0; k0 < QS; k0 += 32) {
        // A tile: 32 rows x 32 k -> transposed into As[kk][row]
        {
            const int r = tid >> 3, c = tid & 7;
            const float4 v = *(const float4*)(A + (size_t)r * QS + k0 + c * 4);
            As[c * 4 + 0][r] = v.x;
            As[c * 4 + 1][r] = v.y;
            As[c * 4 + 2][r] = v.z;
            As[c * 4 + 3][r] = v.w;
        }
        // B tile: 32 k x 128 n
        {
            const int n = (tid & 31) * 4, r0 = tid >> 5;
            #pragma unroll
            for (int j = 0; j < 4; ++j) {
                const int kk = r0 + j * 8;
                *(float4*)&Bs[kk][n] =
                    *(const float4*)(W + (size_t)(k0 + kk) * NN + n);
            }
        }
        __syncthreads();
        #pragma unroll
        for (int kk = 0; kk < 32; ++kk) {
            const float4 a = *(const float4*)&As[kk][q0];
            const float4 b = *(const float4*)&Bs[kk][n0];
            const float av[4] = {a.x, a.y, a.z, a.w};
            const float bv[4] = {b.x, b.y, b.z, b.w};
            #pragma unroll
            for (int i = 0; i < 4; ++i)
                #pragma unroll
                for (int j = 0; j < 4; ++j)
                    acc[i][j] = fmaf(av[i], bv[j], acc[i][j]);
        }
        __syncthreads();
    }

    #pragma unroll
    for (int i = 0; i < 4; ++i) {
        float4 o;
        o.x = acc[i][0] * TANH_SCALE;
        o.y = acc[i][1] * TANH_SCALE;
        o.z = acc[i][2] * TANH_SCALE;
        o.w = acc[i][3] * TANH_SCALE;
        *(float4*)(out + (size_t)(q0 + i) * NN + n0) = o;
    }
}

// ---------------------------------------------------------------------------
// K2: scores + softmax. One block per (b,q); 256 threads; 4 k's per thread
// held in registers; tanh(y) = 1 - 2*rcp(1 + exp2(pre-scaled sum)).
// Writes normalized weights straight to d_out's weights region.
// ---------------------------------------------------------------------------
__global__ __launch_bounds__(256) void score_softmax_kernel(
    const float* __restrict__ attq, const float* __restrict__ attk,
    const float* __restrict__ vatt, float* __restrict__ wout)
{
    __shared__ float4 aqs[32];  // att_query row (pre-scaled), 128 floats
    __shared__ float4 vs[32];   // linear_att, 128 floats
    __shared__ float red[8];

    const int tid = threadIdx.x;
    const int b = blockIdx.x >> 8;
    const int q = blockIdx.x & 255;

    if (tid < 32) {
        aqs[tid] = ((const float4*)(attq + ((size_t)b * TQ + q) * NN))[tid];
    } else if (tid < 64) {
        vs[tid - 32] = ((const float4*)vatt)[tid - 32];
    }
    __syncthreads();

    const float4* akv =
        (const float4*)(attk + ((size_t)b * TK + (size_t)tid * 4) * NN);
    float s[4] = {0.f, 0.f, 0.f, 0.f};

    for (int n4 = 0; n4 < 32; ++n4) {
        const float4 aq = aqs[n4];
        const float4 vv = vs[n4];
        #pragma unroll
        for (int r = 0; r < 4; ++r) {
            const float4 a = akv[r * 32 + n4];
            float x, e, rc, t;
            x = aq.x + a.x; e = fast_exp2(x); rc = fast_rcp(1.0f + e);
            t = fmaf(-2.0f, rc, 1.0f); s[r] = fmaf(vv.x, t, s[r]);
            x = aq.y + a.y; e = fast_exp2(x); rc = fast_rcp(1.0f + e);
            t = fmaf(-2.0f, rc, 1.0f); s[r] = fmaf(vv.y, t, s[r]);
            x = aq.z + a.z; e = fast_exp2(x); rc = fast_rcp(1.0f + e);
            t = fmaf(-2.0f, rc, 1.0f); s[r] = fmaf(vv.z, t, s[r]);
            x = aq.w + a.w; e = fast_exp2(x); rc = fast_rcp(1.0f + e);
            t = fmaf(-2.0f, rc, 1.0f); s[r] = fmaf(vv.w, t, s[r]);
        }
    }

    // --- softmax over 1024 scores (4 per thread, in registers) ---
    const int lane = tid & 63, wid = tid >> 6;
    float m = fmaxf(fmaxf(s[0], s[1]), fmaxf(s[2], s[3]));
    #pragma unroll
    for (int off = 32; off > 0; off >>= 1)
        m = fmaxf(m, __shfl_xor(m, off, 64));
    if (lane == 0) red[wid] = m;
    __syncthreads();
    m = fmaxf(fmaxf(red[0], red[1]), fmaxf(red[2], red[3]));

    float e4[4], ls = 0.f;
    #pragma unroll
    for (int i = 0; i < 4; ++i) {
        e4[i] = fast_exp2((s[i] - m) * LOG2E);
        ls += e4[i];
    }
    #pragma unroll
    for (int off = 32; off > 0; off >>= 1)
        ls += __shfl_xor(ls, off, 64);
    if (lane == 0) red[4 + wid] = ls;
    __syncthreads();
    const float S = red[4] + red[5] + red[6] + red[7];
    const float inv = fast_rcp(S);

    float4 w4;
    w4.x = e4[0] * inv; w4.y = e4[1] * inv;
    w4.z = e4[2] * inv; w4.w = e4[3] * inv;
    *(float4*)(wout + ((size_t)b * TQ + q) * TK + tid * 4) = w4;
}

// ---------------------------------------------------------------------------
// K3: context = weights (256x1024) @ keys (1024x512), per batch.
// Block tile 32q x 64d, BK=32, 256 threads, 2x4 microtile. 256 blocks.
// ---------------------------------------------------------------------------
__global__ __launch_bounds__(256) void context_kernel(
    const float* __restrict__ keys, const float* __restrict__ w,
    float* __restrict__ ctx)
{
    __shared__ float Wst[32][34];  // [kk][q] transposed; pad keeps 8B align
    __shared__ float Ks[32][64];   // [kk][d]

    const int tid = threadIdx.x;
    const int bid = blockIdx.x;
    const int b = bid >> 6;
    const int rem = bid & 63;
    const int qt = rem >> 3;  // 8 q-tiles of 32
    const int dt = rem & 7;   // 8 d-tiles of 64

    const float* wb = w + (size_t)b * TQ * TK + (size_t)qt * 32 * TK;
    const float* kb = keys + (size_t)b * TK * QS + dt * 64;

    const int d0 = (tid & 15) * 4;  // 16 groups cover 64 d
    const int q0 = (tid >> 4) * 2;  // 16 groups cover 32 q
    float acc[2][4] = {};

    for (int k0 = 0; k0 < TK; k0 += 32) {
        // weights tile 32q x 32k -> transposed
        {
            const int r = tid >> 3, c = tid & 7;
            const float4 v = *(const float4*)(wb + (size_t)r * TK + k0 + c * 4);
            Wst[c * 4 + 0][r] = v.x;
            Wst[c * 4 + 1][r] = v.y;
            Wst[c * 4 + 2][r] = v.z;
            Wst[c * 4 + 3][r] = v.w;
        }
        // keys tile 32k x 64d
        {
            const int c = tid & 15, r = tid >> 4;
            *(float4*)&Ks[r][c * 4] =
                *(const float4*)(kb + (size_t)(k0 + r) * QS + c * 4);
            *(float4*)&Ks[r + 16][c * 4] =
                *(const float4*)(kb + (size_t)(k0 + r + 16) * QS + c * 4);
        }
        __syncthreads();
        #pragma unroll
        for (int kk = 0; kk < 32; ++kk) {
            const float2 a = *(const float2*)&Wst[kk][q0];
            const float4 bb = *(const float4*)&Ks[kk][d0];
            acc[0][0] = fmaf(a.x, bb.x, acc[0][0]);
            acc[0][1] = fmaf(a.x, bb.y, acc[0][1]);
            acc[0][2] = fmaf(a.x, bb.z, acc[0][2]);
            acc[0][3] = fmaf(a.x, bb.w, acc[0][3]);
            acc[1][0] = fmaf(a.y, bb.x, acc[1][0]);
            acc[1][1] = fmaf(a.y, bb.y, acc[1][1]);
            acc[1][2] = fmaf(a.y, bb.z, acc[1][2]);
            acc[1][3] = fmaf(a.y, bb.w, acc[1][3]);
        }
        __syncthreads();
    }

    #pragma unroll
    for (int i = 0; i < 2; ++i) {
        float4 o;
        o.x = acc[i][0]; o.y = acc[i][1]; o.z = acc[i][2]; o.w = acc[i][3];
        *(float4*)(ctx + ((size_t)b * TQ + qt * 32 + q0 + i) * QS + dt * 64 + d0) = o;
    }
}

// ---------------------------------------------------------------------------
extern "C" void kernel_launch(void* const* d_in, const int* in_sizes, int n_in,
                              void* d_out, int out_size, void* d_ws, size_t ws_size,
                              hipStream_t stream) {
    const float* query = (const float*)d_in[0];  // (4,256,512)
    const float* keys  = (const float*)d_in[1];  // (4,1024,512)
    const float* Wq    = (const float*)d_in[2];  // (512,128)
    const float* Wk    = (const float*)d_in[3];  // (512,128)
    const float* vatt  = (const float*)d_in[4];  // (128,)

    float* ctx = (float*)d_out;                       // 4*256*512
    float* wts = ctx + (size_t)B * TQ * QS;           // 4*256*1024

    float* attq = (float*)d_ws;                       // 4*256*128
    float* attk = attq + (size_t)B * TQ * NN;         // 4*1024*128

    hipLaunchKernelGGL(proj_kernel, dim3((B * TQ + B * TK) / 32), dim3(256), 0,
                       stream, query, keys, Wq, Wk, attq, attk);
    hipLaunchKernelGGL(score_softmax_kernel, dim3(B * TQ), dim3(256), 0,
                       stream, attq, attk, vatt, wts);
    hipLaunchKernelGGL(context_kernel, dim3(256), dim3(256), 0,
                       stream, keys, wts, ctx);
}

// Round 2
// 163.274 us; speedup vs baseline: 1.5580x; 1.5580x over previous
//
#include <hip/hip_runtime.h>

#define B 4
#define TQ 256
#define TK 1024
#define QS 512
#define NN 128

// exp(2y) = exp2(y * 2*log2(e)); projections are pre-scaled by this in K1.
#define TANH_SCALE 2.8853900817779268f
#define LOG2E 1.4426950408889634f

__device__ __forceinline__ float fast_exp2(float x) {
#if __has_builtin(__builtin_amdgcn_exp2f)
    return __builtin_amdgcn_exp2f(x);
#else
    return exp2f(x);
#endif
}
__device__ __forceinline__ float fast_rcp(float x) {
#if __has_builtin(__builtin_amdgcn_rcpf)
    return __builtin_amdgcn_rcpf(x);
#else
    return 1.0f / x;
#endif
}

// ---------------------------------------------------------------------------
// K1: fused projections. Row space = [1024 query rows ; 4096 keys rows].
// Block: 32 rows x 128 cols, BK=32, 256 threads, 4x4 microtile.
// Query rows -> attq[q][n] (scaled). Keys rows -> attkT[b][n][k] (scaled),
// transposed through LDS (Bs padded to 132 so transpose reads are 2-way max).
// ---------------------------------------------------------------------------
__global__ __launch_bounds__(256) void proj_kernel(
    const float* __restrict__ query, const float* __restrict__ keys,
    const float* __restrict__ Wq, const float* __restrict__ Wk,
    float* __restrict__ attq, float* __restrict__ attkT)
{
    __shared__ float As[32][36];   // [kk][row], transposed
    __shared__ float Bs[32][132];  // [kk][n], padded (132%4==0 keeps 16B align)

    const int tid = threadIdx.x;
    const int rb = blockIdx.x * 32;
    const bool isq = (rb < B * TQ);
    const float* A = isq ? (query + (size_t)rb * QS)
                         : (keys + (size_t)(rb - B * TQ) * QS);
    const float* W = isq ? Wq : Wk;

    const int n0 = (tid & 31) * 4;   // 32 col-groups cover 128 cols
    const int q0 = (tid >> 5) * 4;   // 8 row-groups cover 32 rows
    float acc[4][4] = {};

    for (int k0 = 0; k0 < QS; k0 += 32) {
        {
            const int r = tid >> 3, c = tid & 7;
            const float4 v = *(const float4*)(A + (size_t)r * QS + k0 + c * 4);
            As[c * 4 + 0][r] = v.x;
            As[c * 4 + 1][r] = v.y;
            As[c * 4 + 2][r] = v.z;
            As[c * 4 + 3][r] = v.w;
        }
        {
            const int n = (tid & 31) * 4, r0 = tid >> 5;
            #pragma unroll
            for (int j = 0; j < 4; ++j) {
                const int kk = r0 + j * 8;
                *(float4*)&Bs[kk][n] =
                    *(const float4*)(W + (size_t)(k0 + kk) * NN + n);
            }
        }
        __syncthreads();
        #pragma unroll
        for (int kk = 0; kk < 32; ++kk) {
            const float4 a = *(const float4*)&As[kk][q0];
            const float4 b = *(const float4*)&Bs[kk][n0];
            const float av[4] = {a.x, a.y, a.z, a.w};
            const float bv[4] = {b.x, b.y, b.z, b.w};
            #pragma unroll
            for (int i = 0; i < 4; ++i)
                #pragma unroll
                for (int j = 0; j < 4; ++j)
                    acc[i][j] = fmaf(av[i], bv[j], acc[i][j]);
        }
        __syncthreads();
    }

    if (isq) {
        float* out = attq + (size_t)rb * NN;
        #pragma unroll
        for (int i = 0; i < 4; ++i) {
            float4 o;
            o.x = acc[i][0] * TANH_SCALE;
            o.y = acc[i][1] * TANH_SCALE;
            o.z = acc[i][2] * TANH_SCALE;
            o.w = acc[i][3] * TANH_SCALE;
            *(float4*)(out + (size_t)(q0 + i) * NN + n0) = o;
        }
    } else {
        // stage scaled tile into Bs[k_local][n], then write transposed
        #pragma unroll
        for (int i = 0; i < 4; ++i) {
            float4 o;
            o.x = acc[i][0] * TANH_SCALE;
            o.y = acc[i][1] * TANH_SCALE;
            o.z = acc[i][2] * TANH_SCALE;
            o.w = acc[i][3] * TANH_SCALE;
            *(float4*)&Bs[q0 + i][n0] = o;
        }
        __syncthreads();
        const int rk = rb - B * TQ;
        const int bb = rk >> 10;       // batch
        const int kbase = rk & 1023;   // k offset within batch
        const int n = tid >> 1;        // 0..127
        const int kh = (tid & 1) * 16; // half of the 32 k's
        float* o = attkT + (size_t)bb * NN * TK + (size_t)n * TK + kbase + kh;
        #pragma unroll
        for (int m4 = 0; m4 < 4; ++m4) {
            float4 t;
            t.x = Bs[kh + m4 * 4 + 0][n];
            t.y = Bs[kh + m4 * 4 + 1][n];
            t.z = Bs[kh + m4 * 4 + 2][n];
            t.w = Bs[kh + m4 * 4 + 3][n];
            *(float4*)(o + m4 * 4) = t;
        }
    }
}

// ---------------------------------------------------------------------------
// K2: scores + softmax. Block = (b, q-pair); 256 threads; lane owns 4
// CONTIGUOUS k's (k = tid*4) -> attkT loads are 1KB-contiguous per wave.
// 2 q's per block halve attk re-reads. Also zeroes the ctx region of d_out
// so K3 can accumulate with atomics.
// ---------------------------------------------------------------------------
__global__ __launch_bounds__(256) void score_softmax_kernel(
    const float* __restrict__ attq, const float* __restrict__ attkT,
    const float* __restrict__ vatt, float* __restrict__ wout,
    float4* __restrict__ ctxz)
{
    __shared__ float aqs[2][128];
    __shared__ float vsm[128];
    __shared__ float red[2][8];

    const int tid = threadIdx.x;
    const int b = blockIdx.x >> 7;
    const int q0 = (blockIdx.x & 127) * 2;

    // zero context region: 512 blocks x 256 threads x 16B = 2MB exactly
    ctxz[(size_t)blockIdx.x * 256 + tid] = make_float4(0.f, 0.f, 0.f, 0.f);

    if (tid < 128) {
        aqs[0][tid] = attq[((size_t)b * TQ + q0) * NN + tid];
        vsm[tid] = vatt[tid];
    } else {
        aqs[1][tid & 127] = attq[((size_t)b * TQ + q0 + 1) * NN + (tid & 127)];
    }
    __syncthreads();

    const float* kt = attkT + (size_t)b * NN * TK + (size_t)tid * 4;
    float s[2][4] = {};

    #pragma unroll 4
    for (int n = 0; n < 128; ++n) {
        const float4 a = *(const float4*)(kt + (size_t)n * TK);
        const float a0 = aqs[0][n], a1 = aqs[1][n], vv = vsm[n];
        const float av[4] = {a.x, a.y, a.z, a.w};
        #pragma unroll
        for (int r = 0; r < 4; ++r) {
            const float x0 = a0 + av[r];
            const float t0 = fmaf(-2.f, fast_rcp(1.f + fast_exp2(x0)), 1.f);
            s[0][r] = fmaf(vv, t0, s[0][r]);
            const float x1 = a1 + av[r];
            const float t1 = fmaf(-2.f, fast_rcp(1.f + fast_exp2(x1)), 1.f);
            s[1][r] = fmaf(vv, t1, s[1][r]);
        }
    }

    // --- softmax over 1024 scores per q (4 per thread, in registers) ---
    const int lane = tid & 63, wid = tid >> 6;
    #pragma unroll
    for (int qq = 0; qq < 2; ++qq) {
        float mm = fmaxf(fmaxf(s[qq][0], s[qq][1]), fmaxf(s[qq][2], s[qq][3]));
        #pragma unroll
        for (int off = 32; off > 0; off >>= 1)
            mm = fmaxf(mm, __shfl_xor(mm, off, 64));
        if (lane == 0) red[qq][wid] = mm;
    }
    __syncthreads();
    float m[2];
    m[0] = fmaxf(fmaxf(red[0][0], red[0][1]), fmaxf(red[0][2], red[0][3]));
    m[1] = fmaxf(fmaxf(red[1][0], red[1][1]), fmaxf(red[1][2], red[1][3]));

    float e[2][4];
    #pragma unroll
    for (int qq = 0; qq < 2; ++qq) {
        float ls = 0.f;
        #pragma unroll
        for (int i = 0; i < 4; ++i) {
            e[qq][i] = fast_exp2((s[qq][i] - m[qq]) * LOG2E);
            ls += e[qq][i];
        }
        #pragma unroll
        for (int off = 32; off > 0; off >>= 1)
            ls += __shfl_xor(ls, off, 64);
        if (lane == 0) red[qq][4 + wid] = ls;
    }
    __syncthreads();
    #pragma unroll
    for (int qq = 0; qq < 2; ++qq) {
        const float S = red[qq][4] + red[qq][5] + red[qq][6] + red[qq][7];
        const float inv = fast_rcp(S);
        float4 w4;
        w4.x = e[qq][0] * inv; w4.y = e[qq][1] * inv;
        w4.z = e[qq][2] * inv; w4.w = e[qq][3] * inv;
        *(float4*)(wout + ((size_t)b * TQ + q0 + qq) * TK + (size_t)tid * 4) = w4;
    }
}

// ---------------------------------------------------------------------------
// K3: context = weights (256x1024) @ keys (1024x512), per batch.
// Split-K=2: block tile 32q x 64d x 512k, 256 threads, 2x4 microtile,
// 512 blocks (8 waves/CU). Epilogue: fp32 atomicAdd into zeroed ctx.
// ---------------------------------------------------------------------------
__global__ __launch_bounds__(256) void context_kernel(
    const float* __restrict__ keys, const float* __restrict__ w,
    float* __restrict__ ctx)
{
    __shared__ float Wst[32][34];  // [kk][q] transposed, padded
    __shared__ float Ks[32][64];   // [kk][d]

    const int tid = threadIdx.x;
    const int bid = blockIdx.x;
    const int b = bid >> 7;
    const int rem = bid & 127;
    const int qt = rem >> 4;        // 8 q-tiles of 32
    const int dt = (rem >> 1) & 7;  // 8 d-tiles of 64
    const int ks = rem & 1;         // k-split half

    const float* wb = w + (size_t)b * TQ * TK + (size_t)qt * 32 * TK + ks * 512;
    const float* kb = keys + (size_t)b * TK * QS + (size_t)ks * 512 * QS + dt * 64;

    const int d0 = (tid & 15) * 4;  // 16 groups cover 64 d
    const int q0 = (tid >> 4) * 2;  // 16 groups cover 32 q
    float acc[2][4] = {};

    for (int k0 = 0; k0 < 512; k0 += 32) {
        {
            const int r = tid >> 3, c = tid & 7;
            const float4 v = *(const float4*)(wb + (size_t)r * TK + k0 + c * 4);
            Wst[c * 4 + 0][r] = v.x;
            Wst[c * 4 + 1][r] = v.y;
            Wst[c * 4 + 2][r] = v.z;
            Wst[c * 4 + 3][r] = v.w;
        }
        {
            const int c = tid & 15, r = tid >> 4;
            *(float4*)&Ks[r][c * 4] =
                *(const float4*)(kb + (size_t)(k0 + r) * QS + c * 4);
            *(float4*)&Ks[r + 16][c * 4] =
                *(const float4*)(kb + (size_t)(k0 + r + 16) * QS + c * 4);
        }
        __syncthreads();
        #pragma unroll
        for (int kk = 0; kk < 32; ++kk) {
            const float2 a = *(const float2*)&Wst[kk][q0];
            const float4 bb = *(const float4*)&Ks[kk][d0];
            acc[0][0] = fmaf(a.x, bb.x, acc[0][0]);
            acc[0][1] = fmaf(a.x, bb.y, acc[0][1]);
            acc[0][2] = fmaf(a.x, bb.z, acc[0][2]);
            acc[0][3] = fmaf(a.x, bb.w, acc[0][3]);
            acc[1][0] = fmaf(a.y, bb.x, acc[1][0]);
            acc[1][1] = fmaf(a.y, bb.y, acc[1][1]);
            acc[1][2] = fmaf(a.y, bb.z, acc[1][2]);
            acc[1][3] = fmaf(a.y, bb.w, acc[1][3]);
        }
        __syncthreads();
    }

    float* op = ctx + ((size_t)b * TQ + qt * 32 + q0) * QS + dt * 64 + d0;
    #pragma unroll
    for (int i = 0; i < 2; ++i)
        #pragma unroll
        for (int j = 0; j < 4; ++j)
            atomicAdd(op + (size_t)i * QS + j, acc[i][j]);
}

// ---------------------------------------------------------------------------
extern "C" void kernel_launch(void* const* d_in, const int* in_sizes, int n_in,
                              void* d_out, int out_size, void* d_ws, size_t ws_size,
                              hipStream_t stream) {
    const float* query = (const float*)d_in[0];  // (4,256,512)
    const float* keys  = (const float*)d_in[1];  // (4,1024,512)
    const float* Wq    = (const float*)d_in[2];  // (512,128)
    const float* Wk    = (const float*)d_in[3];  // (512,128)
    const float* vatt  = (const float*)d_in[4];  // (128,)

    float* ctx = (float*)d_out;                       // 4*256*512
    float* wts = ctx + (size_t)B * TQ * QS;           // 4*256*1024

    float* attq  = (float*)d_ws;                      // 4*256*128
    float* attkT = attq + (size_t)B * TQ * NN;        // 4*128*1024 (transposed)

    hipLaunchKernelGGL(proj_kernel, dim3((B * TQ + B * TK) / 32), dim3(256), 0,
                       stream, query, keys, Wq, Wk, attq, attkT);
    hipLaunchKernelGGL(score_softmax_kernel, dim3(B * TQ / 2), dim3(256), 0,
                       stream, attq, attkT, vatt, wts, (float4*)ctx);
    hipLaunchKernelGGL(context_kernel, dim3(512), dim3(256), 0,
                       stream, keys, wts, ctx);
}

// Round 4
// 149.480 us; speedup vs baseline: 1.7018x; 1.0923x over previous
//
#include <hip/hip_runtime.h>

#define B 4
#define TQ 256
#define TK 1024
#define QS 512
#define NN 128

// exp(2y) = exp2(y * 2*log2(e)); projections are pre-scaled by this in K1.
#define TANH_SCALE 2.8853900817779268f
#define LOG2E 1.4426950408889634f

__device__ __forceinline__ float fast_exp2(float x) {
#if __has_builtin(__builtin_amdgcn_exp2f)
    return __builtin_amdgcn_exp2f(x);
#else
    return exp2f(x);
#endif
}
__device__ __forceinline__ float fast_rcp(float x) {
#if __has_builtin(__builtin_amdgcn_rcpf)
    return __builtin_amdgcn_rcpf(x);
#else
    return 1.0f / x;
#endif
}

// ---------------------------------------------------------------------------
// K1: fused projections. Row space = [1024 query rows ; 4096 keys rows].
// Block: 16 rows x 128 cols, BK=32, 256 threads, 2x4 microtile. 320 blocks.
// Query rows -> attq[q][n] (scaled). Keys rows -> attkT[b][n][k] (scaled),
// transposed through LDS.
// ---------------------------------------------------------------------------
__global__ __launch_bounds__(256) void proj_kernel(
    const float* __restrict__ query, const float* __restrict__ keys,
    const float* __restrict__ Wq, const float* __restrict__ Wk,
    float* __restrict__ attq, float* __restrict__ attkT)
{
    __shared__ float As[32][18];   // [kk][row], transposed, padded
    __shared__ float Bs[32][132];  // [kk][n], padded (132%4==0 keeps 16B align)

    const int tid = threadIdx.x;
    const int rb = blockIdx.x * 16;
    const bool isq = (rb < B * TQ);
    const float* A = isq ? (query + (size_t)rb * QS)
                         : (keys + (size_t)(rb - B * TQ) * QS);
    const float* W = isq ? Wq : Wk;

    const int n0 = (tid & 31) * 4;   // 32 col-groups cover 128 cols
    const int q0 = (tid >> 5) * 2;   // 8 row-groups cover 16 rows
    float acc[2][4] = {};

    for (int k0 = 0; k0 < QS; k0 += 32) {
        // A tile: 16 rows x 32 k -> transposed into As[kk][row]
        {
            const int r = tid >> 4, c = tid & 15;
            const float2 v = *(const float2*)(A + (size_t)r * QS + k0 + c * 2);
            As[c * 2 + 0][r] = v.x;
            As[c * 2 + 1][r] = v.y;
        }
        // B tile: 32 k x 128 n
        {
            const int n = (tid & 31) * 4, r0 = tid >> 5;
            #pragma unroll
            for (int j = 0; j < 4; ++j) {
                const int kk = r0 + j * 8;
                *(float4*)&Bs[kk][n] =
                    *(const float4*)(W + (size_t)(k0 + kk) * NN + n);
            }
        }
        __syncthreads();
        #pragma unroll
        for (int kk = 0; kk < 32; ++kk) {
            const float2 a = *(const float2*)&As[kk][q0];
            const float4 b = *(const float4*)&Bs[kk][n0];
            acc[0][0] = fmaf(a.x, b.x, acc[0][0]);
            acc[0][1] = fmaf(a.x, b.y, acc[0][1]);
            acc[0][2] = fmaf(a.x, b.z, acc[0][2]);
            acc[0][3] = fmaf(a.x, b.w, acc[0][3]);
            acc[1][0] = fmaf(a.y, b.x, acc[1][0]);
            acc[1][1] = fmaf(a.y, b.y, acc[1][1]);
            acc[1][2] = fmaf(a.y, b.z, acc[1][2]);
            acc[1][3] = fmaf(a.y, b.w, acc[1][3]);
        }
        __syncthreads();
    }

    if (isq) {
        float* out = attq + (size_t)rb * NN;
        #pragma unroll
        for (int i = 0; i < 2; ++i) {
            float4 o;
            o.x = acc[i][0] * TANH_SCALE;
            o.y = acc[i][1] * TANH_SCALE;
            o.z = acc[i][2] * TANH_SCALE;
            o.w = acc[i][3] * TANH_SCALE;
            *(float4*)(out + (size_t)(q0 + i) * NN + n0) = o;
        }
    } else {
        // stage scaled 16x128 tile into Bs[k_local][n], then write transposed
        #pragma unroll
        for (int i = 0; i < 2; ++i) {
            float4 o;
            o.x = acc[i][0] * TANH_SCALE;
            o.y = acc[i][1] * TANH_SCALE;
            o.z = acc[i][2] * TANH_SCALE;
            o.w = acc[i][3] * TANH_SCALE;
            *(float4*)&Bs[q0 + i][n0] = o;
        }
        __syncthreads();
        const int rk = rb - B * TQ;
        const int bb = rk >> 10;       // batch
        const int kbase = rk & 1023;   // k offset within batch (multiple of 16)
        const int n = tid >> 1;        // 0..127
        const int kh = (tid & 1) * 8;  // half of the 16 k's
        float* o = attkT + (size_t)bb * NN * TK + (size_t)n * TK + kbase + kh;
        #pragma unroll
        for (int m4 = 0; m4 < 2; ++m4) {
            float4 t;
            t.x = Bs[kh + m4 * 4 + 0][n];
            t.y = Bs[kh + m4 * 4 + 1][n];
            t.z = Bs[kh + m4 * 4 + 2][n];
            t.w = Bs[kh + m4 * 4 + 3][n];
            *(float4*)(o + m4 * 4) = t;
        }
    }
}

// ---------------------------------------------------------------------------
// K2: scores + softmax. Block = (b, q-pair); 256 threads; lane owns 4
// CONTIGUOUS k's (k = tid*4) -> attkT loads are 1KB-contiguous per wave.
// ---------------------------------------------------------------------------
__global__ __launch_bounds__(256) void score_softmax_kernel(
    const float* __restrict__ attq, const float* __restrict__ attkT,
    const float* __restrict__ vatt, float* __restrict__ wout)
{
    __shared__ float aqs[2][128];
    __shared__ float vsm[128];
    __shared__ float red[2][8];

    const int tid = threadIdx.x;
    const int b = blockIdx.x >> 7;
    const int q0 = (blockIdx.x & 127) * 2;

    if (tid < 128) {
        aqs[0][tid] = attq[((size_t)b * TQ + q0) * NN + tid];
        vsm[tid] = vatt[tid];
    } else {
        aqs[1][tid & 127] = attq[((size_t)b * TQ + q0 + 1) * NN + (tid & 127)];
    }
    __syncthreads();

    const float* kt = attkT + (size_t)b * NN * TK + (size_t)tid * 4;
    float s[2][4] = {};

    #pragma unroll 8
    for (int n = 0; n < 128; ++n) {
        const float4 a = *(const float4*)(kt + (size_t)n * TK);
        const float a0 = aqs[0][n], a1 = aqs[1][n], vv = vsm[n];
        const float av[4] = {a.x, a.y, a.z, a.w};
        #pragma unroll
        for (int r = 0; r < 4; ++r) {
            const float x0 = a0 + av[r];
            const float t0 = fmaf(-2.f, fast_rcp(1.f + fast_exp2(x0)), 1.f);
            s[0][r] = fmaf(vv, t0, s[0][r]);
            const float x1 = a1 + av[r];
            const float t1 = fmaf(-2.f, fast_rcp(1.f + fast_exp2(x1)), 1.f);
            s[1][r] = fmaf(vv, t1, s[1][r]);
        }
    }

    // --- softmax over 1024 scores per q (4 per thread, in registers) ---
    const int lane = tid & 63, wid = tid >> 6;
    #pragma unroll
    for (int qq = 0; qq < 2; ++qq) {
        float mm = fmaxf(fmaxf(s[qq][0], s[qq][1]), fmaxf(s[qq][2], s[qq][3]));
        #pragma unroll
        for (int off = 32; off > 0; off >>= 1)
            mm = fmaxf(mm, __shfl_xor(mm, off, 64));
        if (lane == 0) red[qq][wid] = mm;
    }
    __syncthreads();
    float m[2];
    m[0] = fmaxf(fmaxf(red[0][0], red[0][1]), fmaxf(red[0][2], red[0][3]));
    m[1] = fmaxf(fmaxf(red[1][0], red[1][1]), fmaxf(red[1][2], red[1][3]));

    float e[2][4];
    #pragma unroll
    for (int qq = 0; qq < 2; ++qq) {
        float ls = 0.f;
        #pragma unroll
        for (int i = 0; i < 4; ++i) {
            e[qq][i] = fast_exp2((s[qq][i] - m[qq]) * LOG2E);
            ls += e[qq][i];
        }
        #pragma unroll
        for (int off = 32; off > 0; off >>= 1)
            ls += __shfl_xor(ls, off, 64);
        if (lane == 0) red[qq][4 + wid] = ls;
    }
    __syncthreads();
    #pragma unroll
    for (int qq = 0; qq < 2; ++qq) {
        const float S = red[qq][4] + red[qq][5] + red[qq][6] + red[qq][7];
        const float inv = fast_rcp(S);
        float4 w4;
        w4.x = e[qq][0] * inv; w4.y = e[qq][1] * inv;
        w4.z = e[qq][2] * inv; w4.w = e[qq][3] * inv;
        *(float4*)(wout + ((size_t)b * TQ + q0 + qq) * TK + (size_t)tid * 4) = w4;
    }
}

// ---------------------------------------------------------------------------
// K3: context partials = weights (256x1024) @ keys (1024x512), per batch,
// split-K=4. Block tile 32q x 64d x 256k, 256 threads, 2x4 microtile,
// 1024 blocks (4 blocks/CU). Writes partials to ws (no atomics).
// ---------------------------------------------------------------------------
#define CTX_ELEMS ((size_t)B * TQ * QS)

__global__ __launch_bounds__(256) void context_kernel(
    const float* __restrict__ keys, const float* __restrict__ w,
    float* __restrict__ ctxp)
{
    __shared__ float Wst[32][34];  // [kk][q] transposed, padded
    __shared__ float Ks[32][64];   // [kk][d]

    const int tid = threadIdx.x;
    const int bid = blockIdx.x;
    const int b = bid >> 8;
    const int rem = bid & 255;
    const int qt = rem >> 5;        // 8 q-tiles of 32
    const int dt = (rem >> 2) & 7;  // 8 d-tiles of 64
    const int ks = rem & 3;         // k-split quarter

    const float* wb = w + (size_t)b * TQ * TK + (size_t)qt * 32 * TK + ks * 256;
    const float* kb = keys + (size_t)b * TK * QS + (size_t)ks * 256 * QS + dt * 64;

    const int d0 = (tid & 15) * 4;  // 16 groups cover 64 d
    const int q0 = (tid >> 4) * 2;  // 16 groups cover 32 q
    float acc[2][4] = {};

    for (int k0 = 0; k0 < 256; k0 += 32) {
        {
            const int r = tid >> 3, c = tid & 7;
            const float4 v = *(const float4*)(wb + (size_t)r * TK + k0 + c * 4);
            Wst[c * 4 + 0][r] = v.x;
            Wst[c * 4 + 1][r] = v.y;
            Wst[c * 4 + 2][r] = v.z;
            Wst[c * 4 + 3][r] = v.w;
        }
        {
            const int c = tid & 15, r = tid >> 4;
            *(float4*)&Ks[r][c * 4] =
                *(const float4*)(kb + (size_t)(k0 + r) * QS + c * 4);
            *(float4*)&Ks[r + 16][c * 4] =
                *(const float4*)(kb + (size_t)(k0 + r + 16) * QS + c * 4);
        }
        __syncthreads();
        #pragma unroll
        for (int kk = 0; kk < 32; ++kk) {
            const float2 a = *(const float2*)&Wst[kk][q0];
            const float4 bb = *(const float4*)&Ks[kk][d0];
            acc[0][0] = fmaf(a.x, bb.x, acc[0][0]);
            acc[0][1] = fmaf(a.x, bb.y, acc[0][1]);
            acc[0][2] = fmaf(a.x, bb.z, acc[0][2]);
            acc[0][3] = fmaf(a.x, bb.w, acc[0][3]);
            acc[1][0] = fmaf(a.y, bb.x, acc[1][0]);
            acc[1][1] = fmaf(a.y, bb.y, acc[1][1]);
            acc[1][2] = fmaf(a.y, bb.z, acc[1][2]);
            acc[1][3] = fmaf(a.y, bb.w, acc[1][3]);
        }
        __syncthreads();
    }

    float* op = ctxp + (size_t)ks * CTX_ELEMS
              + ((size_t)b * TQ + qt * 32 + q0) * QS + dt * 64 + d0;
    #pragma unroll
    for (int i = 0; i < 2; ++i) {
        float4 o;
        o.x = acc[i][0]; o.y = acc[i][1]; o.z = acc[i][2]; o.w = acc[i][3];
        *(float4*)(op + (size_t)i * QS) = o;
    }
}

// ---------------------------------------------------------------------------
// K4: reduce the 4 split-K partials into ctx. 131072 float4 outputs.
// ---------------------------------------------------------------------------
__global__ __launch_bounds__(256) void reduce_kernel(
    const float4* __restrict__ ctxp, float4* __restrict__ ctx)
{
    const size_t idx = (size_t)blockIdx.x * 256 + threadIdx.x;
    const size_t stride = CTX_ELEMS / 4;
    const float4 a = ctxp[idx];
    const float4 b = ctxp[idx + stride];
    const float4 c = ctxp[idx + 2 * stride];
    const float4 d = ctxp[idx + 3 * stride];
    float4 o;
    o.x = (a.x + b.x) + (c.x + d.x);
    o.y = (a.y + b.y) + (c.y + d.y);
    o.z = (a.z + b.z) + (c.z + d.z);
    o.w = (a.w + b.w) + (c.w + d.w);
    ctx[idx] = o;
}

// ---------------------------------------------------------------------------
extern "C" void kernel_launch(void* const* d_in, const int* in_sizes, int n_in,
                              void* d_out, int out_size, void* d_ws, size_t ws_size,
                              hipStream_t stream) {
    const float* query = (const float*)d_in[0];  // (4,256,512)
    const float* keys  = (const float*)d_in[1];  // (4,1024,512)
    const float* Wq    = (const float*)d_in[2];  // (512,128)
    const float* Wk    = (const float*)d_in[3];  // (512,128)
    const float* vatt  = (const float*)d_in[4];  // (128,)

    float* ctx = (float*)d_out;                       // 4*256*512
    float* wts = ctx + CTX_ELEMS;                     // 4*256*1024

    float* attq  = (float*)d_ws;                      // 4*256*128
    float* attkT = attq + (size_t)B * TQ * NN;        // 4*128*1024 (transposed)
    float* ctxp  = attkT + (size_t)B * NN * TK;       // 4 * 4*256*512 partials

    hipLaunchKernelGGL(proj_kernel, dim3((B * TQ + B * TK) / 16), dim3(256), 0,
                       stream, query, keys, Wq, Wk, attq, attkT);
    hipLaunchKernelGGL(score_softmax_kernel, dim3(B * TQ / 2), dim3(256), 0,
                       stream, attq, attkT, vatt, wts);
    hipLaunchKernelGGL(context_kernel, dim3(1024), dim3(256), 0,
                       stream, keys, wts, ctxp);
    hipLaunchKernelGGL(reduce_kernel, dim3((unsigned)(CTX_ELEMS / 4 / 256)), dim3(256), 0,
                       stream, (const float4*)ctxp, (float4*)ctx);
}